// Round 3
// baseline (1686.827 us; speedup 1.0000x reference)
//
#include <hip/hip_runtime.h>
#include <cstdint>
#include <cstddef>

#define D_MODEL 1024
#define D_FF    4096
#define NEXP    8
#define NTOK    8192
#define MAXT    136                 // max 128-row M-tiles across experts (<=135)
#define CAP     (MAXT * 128)        // 17408 padded rows capacity

typedef unsigned short ushort_t;
typedef __attribute__((ext_vector_type(8))) short   short8;
typedef __attribute__((ext_vector_type(4))) float   floatx4;
typedef __attribute__((ext_vector_type(4))) unsigned short ushort4v;

__device__ __forceinline__ ushort_t f2bf(float f) {
    union { float f; uint32_t u; } v; v.f = f;
    uint32_t r = v.u + 0x7fffu + ((v.u >> 16) & 1u);   // RNE
    return (ushort_t)(r >> 16);
}

__device__ __forceinline__ floatx4 mfma16(short8 a, short8 b, floatx4 c) {
    return __builtin_amdgcn_mfma_f32_16x16x32_bf16(a, b, c, 0, 0, 0);
}

// decode padded-row tile id -> (expert, row0); returns 0 if past last tile
__device__ __forceinline__ int tile_decode(const int* __restrict__ counts,
                                           int tm, int& e_out, int& row0) {
    int cnts[NEXP];
#pragma unroll
    for (int e = 0; e < NEXP; ++e) cnts[e] = counts[e];   // independent loads
    int b = 0, t = tm;
#pragma unroll
    for (int e = 0; e < NEXP; ++e) {
        int nt = (cnts[e] + 127) >> 7;
        if (t < nt) { e_out = e; row0 = b + t * 128; return 1; }
        t -= nt; b += nt * 128;
    }
    return 0;
}

// ---------------------------------------------------------------- transpose+cvt (both weights, one dispatch)
// W1:[8][1024][4096] -> W1T:[8][4096][1024] bf16 ; W2:[8][4096][1024] -> W2T:[8][1024][4096] bf16
__global__ __launch_bounds__(256)
void transpose_all(const float* __restrict__ W1, const float* __restrict__ W2,
                   ushort_t* __restrict__ W1T, ushort_t* __restrict__ W2T)
{
    __shared__ float t[64][65];
    int bid = blockIdx.x;
    const float* in; ushort_t* out; int R, C, rt, ct;
    if (bid < 8192) {                       // W1 tiles: 16 r-tiles x 64 c-tiles per expert
        int e = bid >> 10, rem = bid & 1023;
        R = D_MODEL; C = D_FF; rt = rem >> 6; ct = rem & 63;
        in = W1 + (size_t)e * R * C; out = W1T + (size_t)e * R * C;
    } else {                                // W2 tiles: 64 r-tiles x 16 c-tiles per expert
        int e = (bid - 8192) >> 10, rem = bid & 1023;
        R = D_FF; C = D_MODEL; rt = rem >> 4; ct = rem & 15;
        in = W2 + (size_t)e * R * C; out = W2T + (size_t)e * R * C;
    }
    int r0 = rt * 64, c0 = ct * 64, tid = threadIdx.x;
    int lr = tid >> 4, lc4 = (tid & 15) * 4;
#pragma unroll
    for (int p = 0; p < 4; ++p) {
        int rr = p * 16 + lr;
        float4 v = *(const float4*)(in + (size_t)(r0 + rr) * C + c0 + lc4);
        t[rr][lc4] = v.x; t[rr][lc4 + 1] = v.y; t[rr][lc4 + 2] = v.z; t[rr][lc4 + 3] = v.w;
    }
    __syncthreads();
    int orw = tid >> 3, j0 = (tid & 7) * 8;
#pragma unroll
    for (int p = 0; p < 2; ++p) {
        int orow = p * 32 + orw;
        ushort_t pk[8];
#pragma unroll
        for (int i = 0; i < 8; ++i) pk[i] = f2bf(t[j0 + i][orow]);
        *(short8*)(out + (size_t)(c0 + orow) * R + r0 + j0) = *(short8*)pk;
    }
}

// ---------------------------------------------------------------- router
__global__ __launch_bounds__(256)
void router_kernel(const float* __restrict__ x, const float* __restrict__ Wg,
                   const float* __restrict__ bg,
                   int* __restrict__ counts, int* __restrict__ slot_tok,
                   float* __restrict__ slot_p, float* __restrict__ psum)
{
    __shared__ float bsum[NEXP];
    int tid = threadIdx.x;
    if (tid < NEXP) bsum[tid] = 0.f;
    __syncthreads();

    int t = (blockIdx.x * 256 + tid) >> 6;     // one wave per token
    int l = tid & 63;
    const float* xr = x + (size_t)t * D_MODEL;
    float acc[NEXP] = {0.f,0.f,0.f,0.f,0.f,0.f,0.f,0.f};
#pragma unroll 4
    for (int c = 0; c < D_MODEL / 64; ++c) {
        int d = c * 64 + l;
        float xv = xr[d];
        const float4* wr = (const float4*)(Wg + (size_t)d * NEXP);
        float4 w0 = wr[0], w1 = wr[1];
        acc[0] += xv * w0.x; acc[1] += xv * w0.y;
        acc[2] += xv * w0.z; acc[3] += xv * w0.w;
        acc[4] += xv * w1.x; acc[5] += xv * w1.y;
        acc[6] += xv * w1.z; acc[7] += xv * w1.w;
    }
#pragma unroll
    for (int off = 32; off >= 1; off >>= 1)
#pragma unroll
        for (int e = 0; e < NEXP; ++e)
            acc[e] += __shfl_xor(acc[e], off);

    if (l == 0) {
        float lg[NEXP], mx = -1e30f;
#pragma unroll
        for (int e = 0; e < NEXP; ++e) { lg[e] = acc[e] + bg[e]; mx = fmaxf(mx, lg[e]); }
        float pr[NEXP], s = 0.f;
#pragma unroll
        for (int e = 0; e < NEXP; ++e) { pr[e] = __expf(lg[e] - mx); s += pr[e]; }
        float inv = 1.f / s;
#pragma unroll
        for (int e = 0; e < NEXP; ++e) pr[e] *= inv;
        int e0 = 0;
#pragma unroll
        for (int e = 1; e < NEXP; ++e) if (pr[e] > pr[e0]) e0 = e;
        int e1 = (e0 == 0) ? 1 : 0;
#pragma unroll
        for (int e = 0; e < NEXP; ++e) if (e != e0 && pr[e] > pr[e1]) e1 = e;
        float pnorm = 1.f / (pr[e0] + pr[e1]);
        int s0 = atomicAdd(&counts[e0], 1);
        slot_tok[e0 * NTOK + s0] = t; slot_p[e0 * NTOK + s0] = pr[e0] * pnorm;
        int s1 = atomicAdd(&counts[e1], 1);
        slot_tok[e1 * NTOK + s1] = t; slot_p[e1 * NTOK + s1] = pr[e1] * pnorm;
#pragma unroll
        for (int e = 0; e < NEXP; ++e) atomicAdd(&bsum[e], pr[e]);
    }
    __syncthreads();
    if (tid < NEXP) atomicAdd(&psum[tid], bsum[tid]);
}

// ---------------------------------------------------------------- gather x -> xg (bf16)
__global__ __launch_bounds__(256)
void gather_kernel(const float* __restrict__ x, const int* __restrict__ counts,
                   const int* __restrict__ slot_tok, const float* __restrict__ slot_p,
                   ushort_t* __restrict__ xg, float* __restrict__ tok_prob,
                   int* __restrict__ tcount, int* __restrict__ tok2row)
{
    __shared__ int sb[NEXP + 1];
    int row = blockIdx.x, tid = threadIdx.x;
    if (tid == 0) {
        int b = 0;
#pragma unroll
        for (int e = 0; e < NEXP; ++e) { sb[e] = b; b += ((counts[e] + 127) >> 7) << 7; }
        sb[NEXP] = b;
    }
    __syncthreads();
    if (row >= sb[NEXP]) return;
    int e = 0;
    while (e < NEXP - 1 && row >= sb[e + 1]) ++e;
    int lr = row - sb[e];
    int tok = -1; float pr = 0.f;
    if (lr < counts[e]) { tok = slot_tok[e * NTOK + lr]; pr = slot_p[e * NTOK + lr]; }
    if (tid == 0) {
        tok_prob[row] = pr;
        if (tok >= 0) {
            int s = atomicAdd(&tcount[tok], 1);   // 0 or 1
            tok2row[tok * 2 + s] = row;
        }
    }
    ushort_t* dst = xg + (size_t)row * D_MODEL;
    if (tok >= 0) {
        float4 v = ((const float4*)(x + (size_t)tok * D_MODEL))[tid];
        ushort4v o; o.x = f2bf(v.x); o.y = f2bf(v.y); o.z = f2bf(v.z); o.w = f2bf(v.w);
        *(ushort4v*)(dst + tid * 4) = o;
    } else {
        *(ushort4v*)(dst + tid * 4) = ushort4v{0, 0, 0, 0};
    }
}

// ---------------------------------------------------------------- grouped GEMM
// C[128x128] = A[tile rows][K] * B[e][colbase..+128][K]^T  (both bf16, k-contig)
// Register-staged double-buffered K-loop (plain global loads stay in flight
// across the barrier). 4x4 super-tile block swizzle for L2/L3 reuse.
// EPI 0: h = relu(C + b1) -> bf16 Hout (single-barrier 32KB LDS epilogue)
// EPI 1: Yout[row] = C + b2 (f32, direct stores; combined later)
template <int EPI>
__global__ __launch_bounds__(256, 4)
void gemm_tile(const ushort_t* __restrict__ A, const ushort_t* __restrict__ B,
               int K, int N, const int* __restrict__ counts,
               int row_lo, int row_hi,
               ushort_t* __restrict__ Hout, const float* __restrict__ bias,
               float* __restrict__ Yout)
{
    // ---- 4x4 super-tile swizzle: 16 consecutive blocks = 4 cols x 4 tiles
    int NX = gridDim.x;
    int lin = blockIdx.y * NX + blockIdx.x;
    int sid = lin >> 4, wi = lin & 15;
    int nsx = NX >> 2;
    int sx = sid % nsx, sy = sid / nsx;
    int colbase = ((sx << 2) + (wi & 3)) * 128;
    int tm = (sy << 2) + (wi >> 2);

    int e, row0;
    if (!tile_decode(counts, tm, e, row0)) return;
    if (row0 < row_lo || row0 >= row_hi) return;

    __shared__ ushort_t smem[128 * 64 * 2];      // As 16KB | Bs 16KB
    ushort_t* As = smem;
    ushort_t* Bs = smem + 128 * 64;

    int tid = threadIdx.x;
    int w = tid >> 6, l = tid & 63;
    int q = l >> 4, ml = l & 15;
    int wm = w >> 1, wn = w & 1;
    int r8 = l >> 3, ch = l & 7;

    const ushort_t* Ab = A + (size_t)row0 * K;
    const ushort_t* Bb = B + ((size_t)e * N + colbase) * K;

    floatx4 acc[4][4];
#pragma unroll
    for (int i = 0; i < 4; ++i)
#pragma unroll
        for (int j = 0; j < 4; ++j) acc[i][j] = floatx4{0.f, 0.f, 0.f, 0.f};

    short8 sa[4], sb[4];
    int rloc[4];
#pragma unroll
    for (int p = 0; p < 4; ++p) rloc[p] = (p * 4 + w) * 8 + r8;

#define GLOAD(k0)                                                          \
    do {                                                                   \
        _Pragma("unroll")                                                  \
        for (int p = 0; p < 4; ++p) {                                      \
            sa[p] = *(const short8*)(Ab + (size_t)rloc[p] * K + (k0) + ch * 8); \
            sb[p] = *(const short8*)(Bb + (size_t)rloc[p] * K + (k0) + ch * 8); \
        }                                                                  \
    } while (0)

    GLOAD(0);
    int nst = K >> 6;
    for (int s = 0; s < nst; ++s) {
#pragma unroll
        for (int p = 0; p < 4; ++p) {
            int r = rloc[p];
            int c = ch ^ r8;                     // XOR chunk swizzle
            *(short8*)(As + r * 64 + c * 8) = sa[p];
            *(short8*)(Bs + r * 64 + c * 8) = sb[p];
        }
        __syncthreads();
        if (s + 1 < nst) GLOAD((s + 1) << 6);    // prefetch stays in flight over compute
#pragma unroll
        for (int kk = 0; kk < 2; ++kk) {
            int cb = kk * 4 + q;
            short8 av[4], bv[4];
#pragma unroll
            for (int mi = 0; mi < 4; ++mi) {
                int m = wm * 64 + mi * 16 + ml;
                av[mi] = *(const short8*)(As + m * 64 + ((cb ^ (m & 7)) * 8));
            }
#pragma unroll
            for (int ni = 0; ni < 4; ++ni) {
                int n = wn * 64 + ni * 16 + ml;
                bv[ni] = *(const short8*)(Bs + n * 64 + ((cb ^ (n & 7)) * 8));
            }
#pragma unroll
            for (int mi = 0; mi < 4; ++mi)
#pragma unroll
                for (int ni = 0; ni < 4; ++ni)
                    acc[mi][ni] = mfma16(av[mi], bv[ni], acc[mi][ni]);
        }
        __syncthreads();
    }
#undef GLOAD

    float bv4[4];
#pragma unroll
    for (int ni = 0; ni < 4; ++ni)
        bv4[ni] = bias[e * N + colbase + wn * 64 + ni * 16 + ml];

    if (EPI == 0) {
        // single-barrier epilogue: full 128x128 bf16 tile in the 32KB smem
        ushort_t* ct = smem;
#pragma unroll
        for (int mi = 0; mi < 4; ++mi)
#pragma unroll
            for (int ni = 0; ni < 4; ++ni)
#pragma unroll
                for (int r = 0; r < 4; ++r) {
                    float v = acc[mi][ni][r] + bv4[ni];
                    v = v > 0.f ? v : 0.f;
                    ct[(wm * 64 + mi * 16 + q * 4 + r) * 128 + wn * 64 + ni * 16 + ml] = f2bf(v);
                }
        __syncthreads();
#pragma unroll
        for (int i = 0; i < 8; ++i) {
            int idx = tid + i * 256;             // 2048 chunks of 16B
            int r = idx >> 4, c8 = idx & 15;
            *(short8*)(Hout + (size_t)(row0 + r) * D_FF + colbase + c8 * 8) =
                *(const short8*)(ct + r * 128 + c8 * 8);
        }
    } else {
#pragma unroll
        for (int mi = 0; mi < 4; ++mi)
#pragma unroll
            for (int ni = 0; ni < 4; ++ni)
#pragma unroll
                for (int r = 0; r < 4; ++r) {
                    int row = row0 + wm * 64 + mi * 16 + q * 4 + r;
                    int col = colbase + wn * 64 + ni * 16 + ml;
                    Yout[(size_t)row * N + col] = acc[mi][ni][r] + bv4[ni];
                }
    }
}

// ---------------------------------------------------------------- combine (+loss)
__global__ __launch_bounds__(256)
void combine_kernel(const float* __restrict__ y, const int* __restrict__ tok2row,
                    const float* __restrict__ tok_prob, float* __restrict__ out,
                    const float* __restrict__ psum, float* __restrict__ loss_out)
{
    int t = blockIdx.x;
    if (t == 0 && threadIdx.x == 0) {
        float me[NEXP], m = 0.f;
#pragma unroll
        for (int e = 0; e < NEXP; ++e) { me[e] = psum[e] * (1.f / NTOK); m += me[e] * (1.f / NEXP); }
        float v = 0.f;
#pragma unroll
        for (int e = 0; e < NEXP; ++e) v += (me[e] - m) * (me[e] - m);
        loss_out[0] = v * (1.f / (NEXP - 1));
    }
    int r0 = tok2row[t * 2], r1 = tok2row[t * 2 + 1];
    float p0 = tok_prob[r0], p1 = tok_prob[r1];
    int c = threadIdx.x;
    float4 a = ((const float4*)(y + (size_t)r0 * D_MODEL))[c];
    float4 b = ((const float4*)(y + (size_t)r1 * D_MODEL))[c];
    float4 o;
    o.x = p0 * a.x + p1 * b.x;
    o.y = p0 * a.y + p1 * b.y;
    o.z = p0 * a.z + p1 * b.z;
    o.w = p0 * a.w + p1 * b.w;
    ((float4*)(out + (size_t)t * D_MODEL))[c] = o;
}

// ---------------------------------------------------------------- launch
extern "C" void kernel_launch(void* const* d_in, const int* in_sizes, int n_in,
                              void* d_out, int out_size, void* d_ws, size_t ws_size,
                              hipStream_t stream)
{
    const float* x  = (const float*)d_in[0];
    const float* Wg = (const float*)d_in[1];
    const float* bg = (const float*)d_in[2];
    const float* W1 = (const float*)d_in[3];
    const float* b1 = (const float*)d_in[4];
    const float* W2 = (const float*)d_in[5];
    const float* b2 = (const float*)d_in[6];
    float* out = (float*)d_out;

    char* ws = (char*)d_ws;
    size_t off = 0;
    auto alloc = [&](size_t bytes) -> char* {
        char* p = ws + off;
        off = (off + bytes + 255) & ~(size_t)255;
        return p;
    };
    // zero-initialized region first (one memset covers it)
    int*      counts   = (int*)alloc(NEXP * 4);
    float*    psum     = (float*)alloc(NEXP * 4);
    int*      tcount   = (int*)alloc(NTOK * 4);
    size_t zero_bytes = off;
    // rest
    float*    tok_prob = (float*)alloc(CAP * 4);
    int*      tok2row  = (int*)alloc((size_t)NTOK * 2 * 4);
    int*      slot_tok = (int*)alloc((size_t)NEXP * NTOK * 4);
    float*    slot_p   = (float*)alloc((size_t)NEXP * NTOK * 4);
    ushort_t* xg       = (ushort_t*)alloc((size_t)CAP * D_MODEL * 2);
    ushort_t* W1T      = (ushort_t*)alloc((size_t)NEXP * D_MODEL * D_FF * 2);
    ushort_t* W2T      = (ushort_t*)alloc((size_t)NEXP * D_MODEL * D_FF * 2);
    float*    ybuf     = (float*)alloc((size_t)CAP * D_MODEL * 4);
    size_t fixed = off;
    size_t h_full = (size_t)CAP * D_FF * 2;

    int NC = 1;                                    // chunk h if ws is small
    if (ws_size < fixed + h_full) NC = 4;
    if (NC == 4 && ws_size < fixed + h_full / 4) NC = 16;
    if (ws_size < fixed + h_full / NC) return;     // cannot run safely
    int chunk_rows = CAP / NC;
    ushort_t* hbuf = (ushort_t*)alloc(h_full / NC);

    hipMemsetAsync(d_ws, 0, zero_bytes, stream);   // counts + psum + tcount

    transpose_all<<<16384, 256, 0, stream>>>(W1, W2, W1T, W2T);
    router_kernel<<<NTOK / 4, 256, 0, stream>>>(x, Wg, bg, counts, slot_tok, slot_p, psum);
    gather_kernel<<<CAP, 256, 0, stream>>>(x, counts, slot_tok, slot_p, xg,
                                           tok_prob, tcount, tok2row);
    for (int c = 0; c < NC; ++c) {
        int lo = c * chunk_rows, hi = lo + chunk_rows;
        ushort_t* h_eff = hbuf - (ptrdiff_t)lo * D_FF;   // abs-row indexed view
        gemm_tile<0><<<dim3(D_FF / 128, MAXT), 256, 0, stream>>>(
            xg, W1T, D_MODEL, D_FF, counts, lo, hi, h_eff, b1, nullptr);
        gemm_tile<1><<<dim3(D_MODEL / 128, MAXT), 256, 0, stream>>>(
            h_eff, W2T, D_FF, D_MODEL, counts, lo, hi, nullptr, b2, ybuf);
    }
    combine_kernel<<<NTOK, 256, 0, stream>>>(ybuf, tok2row, tok_prob, out, psum,
                                             out + (size_t)out_size - 1);
    (void)in_sizes; (void)n_in;
}

// Round 4
// 901.821 us; speedup vs baseline: 1.8705x; 1.8705x over previous
//
#include <hip/hip_runtime.h>
#include <cstdint>
#include <cstddef>

#define D_MODEL 1024
#define D_FF    4096
#define NEXP    8
#define NTOK    8192
#define MAXT    136                 // max 128-row M-tiles across experts (<=135)
#define CAP     (MAXT * 128)        // 17408 padded rows capacity

typedef unsigned short ushort_t;
typedef __attribute__((ext_vector_type(8))) short   short8;
typedef __attribute__((ext_vector_type(4))) float   floatx4;
typedef __attribute__((ext_vector_type(4))) unsigned short ushort4v;

__device__ __forceinline__ ushort_t f2bf(float f) {
    union { float f; uint32_t u; } v; v.f = f;
    uint32_t r = v.u + 0x7fffu + ((v.u >> 16) & 1u);   // RNE
    return (ushort_t)(r >> 16);
}

__device__ __forceinline__ floatx4 mfma16(short8 a, short8 b, floatx4 c) {
    return __builtin_amdgcn_mfma_f32_16x16x32_bf16(a, b, c, 0, 0, 0);
}

// decode padded-row tile id -> (expert, row0); returns 0 if past last tile
__device__ __forceinline__ int tile_decode(const int* __restrict__ counts,
                                           int tm, int& e_out, int& row0) {
    int cnts[NEXP];
#pragma unroll
    for (int e = 0; e < NEXP; ++e) cnts[e] = counts[e];   // independent loads
    int b = 0, t = tm;
#pragma unroll
    for (int e = 0; e < NEXP; ++e) {
        int nt = (cnts[e] + 127) >> 7;
        if (t < nt) { e_out = e; row0 = b + t * 128; return 1; }
        t -= nt; b += nt * 128;
    }
    return 0;
}

// ---------------------------------------------------------------- transpose+cvt (both weights, one dispatch)
// W1:[8][1024][4096] -> W1T:[8][4096][1024] bf16 ; W2:[8][4096][1024] -> W2T:[8][1024][4096] bf16
__global__ __launch_bounds__(256)
void transpose_all(const float* __restrict__ W1, const float* __restrict__ W2,
                   ushort_t* __restrict__ W1T, ushort_t* __restrict__ W2T)
{
    __shared__ float t[64][65];
    int bid = blockIdx.x;
    const float* in; ushort_t* out; int R, C, rt, ct;
    if (bid < 8192) {                       // W1 tiles: 16 r-tiles x 64 c-tiles per expert
        int e = bid >> 10, rem = bid & 1023;
        R = D_MODEL; C = D_FF; rt = rem >> 6; ct = rem & 63;
        in = W1 + (size_t)e * R * C; out = W1T + (size_t)e * R * C;
    } else {                                // W2 tiles: 64 r-tiles x 16 c-tiles per expert
        int e = (bid - 8192) >> 10, rem = bid & 1023;
        R = D_FF; C = D_MODEL; rt = rem >> 4; ct = rem & 15;
        in = W2 + (size_t)e * R * C; out = W2T + (size_t)e * R * C;
    }
    int r0 = rt * 64, c0 = ct * 64, tid = threadIdx.x;
    int lr = tid >> 4, lc4 = (tid & 15) * 4;
#pragma unroll
    for (int p = 0; p < 4; ++p) {
        int rr = p * 16 + lr;
        float4 v = *(const float4*)(in + (size_t)(r0 + rr) * C + c0 + lc4);
        t[rr][lc4] = v.x; t[rr][lc4 + 1] = v.y; t[rr][lc4 + 2] = v.z; t[rr][lc4 + 3] = v.w;
    }
    __syncthreads();
    int orw = tid >> 3, j0 = (tid & 7) * 8;
#pragma unroll
    for (int p = 0; p < 2; ++p) {
        int orow = p * 32 + orw;
        ushort_t pk[8];
#pragma unroll
        for (int i = 0; i < 8; ++i) pk[i] = f2bf(t[j0 + i][orow]);
        *(short8*)(out + (size_t)(c0 + orow) * R + r0 + j0) = *(short8*)pk;
    }
}

// ---------------------------------------------------------------- router
__global__ __launch_bounds__(256)
void router_kernel(const float* __restrict__ x, const float* __restrict__ Wg,
                   const float* __restrict__ bg,
                   int* __restrict__ counts, int* __restrict__ slot_tok,
                   float* __restrict__ slot_p, float* __restrict__ psum)
{
    __shared__ float bsum[NEXP];
    int tid = threadIdx.x;
    if (tid < NEXP) bsum[tid] = 0.f;
    __syncthreads();

    int t = (blockIdx.x * 256 + tid) >> 6;     // one wave per token
    int l = tid & 63;
    const float* xr = x + (size_t)t * D_MODEL;
    float acc[NEXP] = {0.f,0.f,0.f,0.f,0.f,0.f,0.f,0.f};
#pragma unroll 4
    for (int c = 0; c < D_MODEL / 64; ++c) {
        int d = c * 64 + l;
        float xv = xr[d];
        const float4* wr = (const float4*)(Wg + (size_t)d * NEXP);
        float4 w0 = wr[0], w1 = wr[1];
        acc[0] += xv * w0.x; acc[1] += xv * w0.y;
        acc[2] += xv * w0.z; acc[3] += xv * w0.w;
        acc[4] += xv * w1.x; acc[5] += xv * w1.y;
        acc[6] += xv * w1.z; acc[7] += xv * w1.w;
    }
#pragma unroll
    for (int off = 32; off >= 1; off >>= 1)
#pragma unroll
        for (int e = 0; e < NEXP; ++e)
            acc[e] += __shfl_xor(acc[e], off);

    if (l == 0) {
        float lg[NEXP], mx = -1e30f;
#pragma unroll
        for (int e = 0; e < NEXP; ++e) { lg[e] = acc[e] + bg[e]; mx = fmaxf(mx, lg[e]); }
        float pr[NEXP], s = 0.f;
#pragma unroll
        for (int e = 0; e < NEXP; ++e) { pr[e] = __expf(lg[e] - mx); s += pr[e]; }
        float inv = 1.f / s;
#pragma unroll
        for (int e = 0; e < NEXP; ++e) pr[e] *= inv;
        int e0 = 0;
#pragma unroll
        for (int e = 1; e < NEXP; ++e) if (pr[e] > pr[e0]) e0 = e;
        int e1 = (e0 == 0) ? 1 : 0;
#pragma unroll
        for (int e = 0; e < NEXP; ++e) if (e != e0 && pr[e] > pr[e1]) e1 = e;
        float pnorm = 1.f / (pr[e0] + pr[e1]);
        int s0 = atomicAdd(&counts[e0], 1);
        slot_tok[e0 * NTOK + s0] = t; slot_p[e0 * NTOK + s0] = pr[e0] * pnorm;
        int s1 = atomicAdd(&counts[e1], 1);
        slot_tok[e1 * NTOK + s1] = t; slot_p[e1 * NTOK + s1] = pr[e1] * pnorm;
#pragma unroll
        for (int e = 0; e < NEXP; ++e) atomicAdd(&bsum[e], pr[e]);
    }
    __syncthreads();
    if (tid < NEXP) atomicAdd(&psum[tid], bsum[tid]);
}

// ---------------------------------------------------------------- gather x -> xg (bf16)
__global__ __launch_bounds__(256)
void gather_kernel(const float* __restrict__ x, const int* __restrict__ counts,
                   const int* __restrict__ slot_tok, const float* __restrict__ slot_p,
                   ushort_t* __restrict__ xg, float* __restrict__ tok_prob,
                   int* __restrict__ tcount, int* __restrict__ tok2row)
{
    __shared__ int sb[NEXP + 1];
    int row = blockIdx.x, tid = threadIdx.x;
    if (tid == 0) {
        int b = 0;
#pragma unroll
        for (int e = 0; e < NEXP; ++e) { sb[e] = b; b += ((counts[e] + 127) >> 7) << 7; }
        sb[NEXP] = b;
    }
    __syncthreads();
    if (row >= sb[NEXP]) return;
    int e = 0;
    while (e < NEXP - 1 && row >= sb[e + 1]) ++e;
    int lr = row - sb[e];
    int tok = -1; float pr = 0.f;
    if (lr < counts[e]) { tok = slot_tok[e * NTOK + lr]; pr = slot_p[e * NTOK + lr]; }
    if (tid == 0) {
        tok_prob[row] = pr;
        if (tok >= 0) {
            int s = atomicAdd(&tcount[tok], 1);   // 0 or 1
            tok2row[tok * 2 + s] = row;
        }
    }
    ushort_t* dst = xg + (size_t)row * D_MODEL;
    if (tok >= 0) {
        float4 v = ((const float4*)(x + (size_t)tok * D_MODEL))[tid];
        ushort4v o; o.x = f2bf(v.x); o.y = f2bf(v.y); o.z = f2bf(v.z); o.w = f2bf(v.w);
        *(ushort4v*)(dst + tid * 4) = o;
    } else {
        *(ushort4v*)(dst + tid * 4) = ushort4v{0, 0, 0, 0};
    }
}

// ---------------------------------------------------------------- grouped GEMM
// C[128x128] = A[tile rows][K] * B[e][colbase..+128][K]^T  (both bf16, k-contig)
// Register-staged double-buffered K-loop (plain global loads stay in flight
// across the barrier). 4x4 super-tile block swizzle for L2/L3 reuse.
// __launch_bounds__(256,2): (256,4) caps VGPR at 64 -> massive scratch spill
// (round 3: WRITE_SIZE 67MB -> 1.4GB, 3x slowdown). 76 VGPRs needs >=2/SIMD cap.
// EPI 0: h = relu(C + b1) -> bf16 Hout (single-barrier 32KB LDS epilogue)
// EPI 1: Yout[row] = C + b2 (f32, direct stores; combined later)
template <int EPI>
__global__ __launch_bounds__(256, 2)
void gemm_tile(const ushort_t* __restrict__ A, const ushort_t* __restrict__ B,
               int K, int N, const int* __restrict__ counts,
               int row_lo, int row_hi,
               ushort_t* __restrict__ Hout, const float* __restrict__ bias,
               float* __restrict__ Yout)
{
    // ---- 4x4 super-tile swizzle: 16 consecutive blocks = 4 cols x 4 tiles
    int NX = gridDim.x;
    int lin = blockIdx.y * NX + blockIdx.x;
    int sid = lin >> 4, wi = lin & 15;
    int nsx = NX >> 2;
    int sx = sid % nsx, sy = sid / nsx;
    int colbase = ((sx << 2) + (wi & 3)) * 128;
    int tm = (sy << 2) + (wi >> 2);

    int e, row0;
    if (!tile_decode(counts, tm, e, row0)) return;
    if (row0 < row_lo || row0 >= row_hi) return;

    __shared__ ushort_t smem[128 * 64 * 2];      // As 16KB | Bs 16KB
    ushort_t* As = smem;
    ushort_t* Bs = smem + 128 * 64;

    int tid = threadIdx.x;
    int w = tid >> 6, l = tid & 63;
    int q = l >> 4, ml = l & 15;
    int wm = w >> 1, wn = w & 1;
    int r8 = l >> 3, ch = l & 7;

    const ushort_t* Ab = A + (size_t)row0 * K;
    const ushort_t* Bb = B + ((size_t)e * N + colbase) * K;

    floatx4 acc[4][4];
#pragma unroll
    for (int i = 0; i < 4; ++i)
#pragma unroll
        for (int j = 0; j < 4; ++j) acc[i][j] = floatx4{0.f, 0.f, 0.f, 0.f};

    short8 sa[4], sb[4];
    int rloc[4];
#pragma unroll
    for (int p = 0; p < 4; ++p) rloc[p] = (p * 4 + w) * 8 + r8;

#define GLOAD(k0)                                                          \
    do {                                                                   \
        _Pragma("unroll")                                                  \
        for (int p = 0; p < 4; ++p) {                                      \
            sa[p] = *(const short8*)(Ab + (size_t)rloc[p] * K + (k0) + ch * 8); \
            sb[p] = *(const short8*)(Bb + (size_t)rloc[p] * K + (k0) + ch * 8); \
        }                                                                  \
    } while (0)

    GLOAD(0);
    int nst = K >> 6;
    for (int s = 0; s < nst; ++s) {
#pragma unroll
        for (int p = 0; p < 4; ++p) {
            int r = rloc[p];
            int c = ch ^ r8;                     // XOR chunk swizzle
            *(short8*)(As + r * 64 + c * 8) = sa[p];
            *(short8*)(Bs + r * 64 + c * 8) = sb[p];
        }
        __syncthreads();
        if (s + 1 < nst) GLOAD((s + 1) << 6);    // prefetch stays in flight over compute
#pragma unroll
        for (int kk = 0; kk < 2; ++kk) {
            int cb = kk * 4 + q;
            short8 av[4], bv[4];
#pragma unroll
            for (int mi = 0; mi < 4; ++mi) {
                int m = wm * 64 + mi * 16 + ml;
                av[mi] = *(const short8*)(As + m * 64 + ((cb ^ (m & 7)) * 8));
            }
#pragma unroll
            for (int ni = 0; ni < 4; ++ni) {
                int n = wn * 64 + ni * 16 + ml;
                bv[ni] = *(const short8*)(Bs + n * 64 + ((cb ^ (n & 7)) * 8));
            }
#pragma unroll
            for (int mi = 0; mi < 4; ++mi)
#pragma unroll
                for (int ni = 0; ni < 4; ++ni)
                    acc[mi][ni] = mfma16(av[mi], bv[ni], acc[mi][ni]);
        }
        __syncthreads();
    }
#undef GLOAD

    float bv4[4];
#pragma unroll
    for (int ni = 0; ni < 4; ++ni)
        bv4[ni] = bias[e * N + colbase + wn * 64 + ni * 16 + ml];

    if (EPI == 0) {
        // single-barrier epilogue: full 128x128 bf16 tile in the 32KB smem
        ushort_t* ct = smem;
#pragma unroll
        for (int mi = 0; mi < 4; ++mi)
#pragma unroll
            for (int ni = 0; ni < 4; ++ni)
#pragma unroll
                for (int r = 0; r < 4; ++r) {
                    float v = acc[mi][ni][r] + bv4[ni];
                    v = v > 0.f ? v : 0.f;
                    ct[(wm * 64 + mi * 16 + q * 4 + r) * 128 + wn * 64 + ni * 16 + ml] = f2bf(v);
                }
        __syncthreads();
#pragma unroll
        for (int i = 0; i < 8; ++i) {
            int idx = tid + i * 256;             // 2048 chunks of 16B
            int r = idx >> 4, c8 = idx & 15;
            *(short8*)(Hout + (size_t)(row0 + r) * D_FF + colbase + c8 * 8) =
                *(const short8*)(ct + r * 128 + c8 * 8);
        }
    } else {
#pragma unroll
        for (int mi = 0; mi < 4; ++mi)
#pragma unroll
            for (int ni = 0; ni < 4; ++ni)
#pragma unroll
                for (int r = 0; r < 4; ++r) {
                    int row = row0 + wm * 64 + mi * 16 + q * 4 + r;
                    int col = colbase + wn * 64 + ni * 16 + ml;
                    Yout[(size_t)row * N + col] = acc[mi][ni][r] + bv4[ni];
                }
    }
}

// ---------------------------------------------------------------- combine (+loss)
__global__ __launch_bounds__(256)
void combine_kernel(const float* __restrict__ y, const int* __restrict__ tok2row,
                    const float* __restrict__ tok_prob, float* __restrict__ out,
                    const float* __restrict__ psum, float* __restrict__ loss_out)
{
    int t = blockIdx.x;
    if (t == 0 && threadIdx.x == 0) {
        float me[NEXP], m = 0.f;
#pragma unroll
        for (int e = 0; e < NEXP; ++e) { me[e] = psum[e] * (1.f / NTOK); m += me[e] * (1.f / NEXP); }
        float v = 0.f;
#pragma unroll
        for (int e = 0; e < NEXP; ++e) v += (me[e] - m) * (me[e] - m);
        loss_out[0] = v * (1.f / (NEXP - 1));
    }
    int r0 = tok2row[t * 2], r1 = tok2row[t * 2 + 1];
    float p0 = tok_prob[r0], p1 = tok_prob[r1];
    int c = threadIdx.x;
    float4 a = ((const float4*)(y + (size_t)r0 * D_MODEL))[c];
    float4 b = ((const float4*)(y + (size_t)r1 * D_MODEL))[c];
    float4 o;
    o.x = p0 * a.x + p1 * b.x;
    o.y = p0 * a.y + p1 * b.y;
    o.z = p0 * a.z + p1 * b.z;
    o.w = p0 * a.w + p1 * b.w;
    ((float4*)(out + (size_t)t * D_MODEL))[c] = o;
}

// ---------------------------------------------------------------- launch
extern "C" void kernel_launch(void* const* d_in, const int* in_sizes, int n_in,
                              void* d_out, int out_size, void* d_ws, size_t ws_size,
                              hipStream_t stream)
{
    const float* x  = (const float*)d_in[0];
    const float* Wg = (const float*)d_in[1];
    const float* bg = (const float*)d_in[2];
    const float* W1 = (const float*)d_in[3];
    const float* b1 = (const float*)d_in[4];
    const float* W2 = (const float*)d_in[5];
    const float* b2 = (const float*)d_in[6];
    float* out = (float*)d_out;

    char* ws = (char*)d_ws;
    size_t off = 0;
    auto alloc = [&](size_t bytes) -> char* {
        char* p = ws + off;
        off = (off + bytes + 255) & ~(size_t)255;
        return p;
    };
    // zero-initialized region first (one memset covers it)
    int*      counts   = (int*)alloc(NEXP * 4);
    float*    psum     = (float*)alloc(NEXP * 4);
    int*      tcount   = (int*)alloc(NTOK * 4);
    size_t zero_bytes = off;
    // rest
    float*    tok_prob = (float*)alloc(CAP * 4);
    int*      tok2row  = (int*)alloc((size_t)NTOK * 2 * 4);
    int*      slot_tok = (int*)alloc((size_t)NEXP * NTOK * 4);
    float*    slot_p   = (float*)alloc((size_t)NEXP * NTOK * 4);
    ushort_t* xg       = (ushort_t*)alloc((size_t)CAP * D_MODEL * 2);
    ushort_t* W1T      = (ushort_t*)alloc((size_t)NEXP * D_MODEL * D_FF * 2);
    ushort_t* W2T      = (ushort_t*)alloc((size_t)NEXP * D_MODEL * D_FF * 2);
    float*    ybuf     = (float*)alloc((size_t)CAP * D_MODEL * 4);
    size_t fixed = off;
    size_t h_full = (size_t)CAP * D_FF * 2;

    int NC = 1;                                    // chunk h if ws is small
    if (ws_size < fixed + h_full) NC = 4;
    if (NC == 4 && ws_size < fixed + h_full / 4) NC = 16;
    if (ws_size < fixed + h_full / NC) return;     // cannot run safely
    int chunk_rows = CAP / NC;
    ushort_t* hbuf = (ushort_t*)alloc(h_full / NC);

    hipMemsetAsync(d_ws, 0, zero_bytes, stream);   // counts + psum + tcount

    transpose_all<<<16384, 256, 0, stream>>>(W1, W2, W1T, W2T);
    router_kernel<<<NTOK / 4, 256, 0, stream>>>(x, Wg, bg, counts, slot_tok, slot_p, psum);
    gather_kernel<<<CAP, 256, 0, stream>>>(x, counts, slot_tok, slot_p, xg,
                                           tok_prob, tcount, tok2row);
    for (int c = 0; c < NC; ++c) {
        int lo = c * chunk_rows, hi = lo + chunk_rows;
        ushort_t* h_eff = hbuf - (ptrdiff_t)lo * D_FF;   // abs-row indexed view
        gemm_tile<0><<<dim3(D_FF / 128, MAXT), 256, 0, stream>>>(
            xg, W1T, D_MODEL, D_FF, counts, lo, hi, h_eff, b1, nullptr);
        gemm_tile<1><<<dim3(D_MODEL / 128, MAXT), 256, 0, stream>>>(
            h_eff, W2T, D_FF, D_MODEL, counts, lo, hi, nullptr, b2, ybuf);
    }
    combine_kernel<<<NTOK, 256, 0, stream>>>(ybuf, tok2row, tok_prob, out, psum,
                                             out + (size_t)out_size - 1);
    (void)in_sizes; (void)n_in;
}